// Round 1
// baseline (2521.864 us; speedup 1.0000x reference)
//
#include <hip/hip_runtime.h>
#include <type_traits>

#define HID 256
#define PTS 64          // points per block
#define NLAYERS 10

// activation selector: m = layer % 4 : 0 sin, 1 cos, 2 gaussian, 3 tanh
template <int M>
__device__ __forceinline__ float act(float z) {
    if constexpr (M == 0) return __sinf(z);
    else if constexpr (M == 1) return __cosf(z);
    else if constexpr (M == 2) return __expf(-z * z);
    else { float e = __expf(2.0f * z); return 1.0f - 2.0f / (e + 1.0f); }
}

__global__ __launch_bounds__(256, 2) void cppn_fused(
    const float* __restrict__ x,    // (N,12)
    const float* __restrict__ W0,   // (12,256)
    const float* __restrict__ b0,   // (256,)
    const float* __restrict__ Ws,   // (9,256,256)
    const float* __restrict__ bs,   // (9,256)
    const float* __restrict__ Wout, // (256,3)
    const float* __restrict__ bout, // (3,)
    float* __restrict__ out,        // (N,3)
    int n)
{
    __shared__ float h[HID][PTS];   // 64 KB, h[k][p]: lane-consecutive, conflict-free

    const int tid  = threadIdx.x;
    const int p    = tid & 63;                                     // lane = point
    const int j0   = __builtin_amdgcn_readfirstlane((tid >> 6) << 6); // wave's 64-out slice
    const long pg  = (long)blockIdx.x * PTS + p;                   // global point
    const bool live = (pg < n);

    // ---------------- layer 0: x(12) @ W0 + b0, sin ----------------
    {
        float xv[12];
        if (live) {
            const float4* xr = (const float4*)(x + pg * 12);
            float4 a = xr[0], b = xr[1], c = xr[2];
            xv[0]=a.x; xv[1]=a.y; xv[2]=a.z;  xv[3]=a.w;
            xv[4]=b.x; xv[5]=b.y; xv[6]=b.z;  xv[7]=b.w;
            xv[8]=c.x; xv[9]=c.y; xv[10]=c.z; xv[11]=c.w;
        } else {
            #pragma unroll
            for (int k = 0; k < 12; ++k) xv[k] = 0.0f;
        }
        float acc[64];
        #pragma unroll
        for (int q = 0; q < 64; ++q) acc[q] = 0.0f;
        #pragma unroll
        for (int k = 0; k < 12; ++k) {
            const float a = xv[k];
            const float4* wr = (const float4*)(W0 + k * HID + j0);
            #pragma unroll
            for (int q = 0; q < 16; ++q) {
                float4 w = wr[q];
                acc[4*q+0] = fmaf(a, w.x, acc[4*q+0]);
                acc[4*q+1] = fmaf(a, w.y, acc[4*q+1]);
                acc[4*q+2] = fmaf(a, w.z, acc[4*q+2]);
                acc[4*q+3] = fmaf(a, w.w, acc[4*q+3]);
            }
        }
        #pragma unroll
        for (int q = 0; q < 16; ++q) {
            float4 b4 = *(const float4*)(b0 + j0 + 4*q);
            h[j0+4*q+0][p] = act<0>(acc[4*q+0] + b4.x);
            h[j0+4*q+1][p] = act<0>(acc[4*q+1] + b4.y);
            h[j0+4*q+2][p] = act<0>(acc[4*q+2] + b4.z);
            h[j0+4*q+3][p] = act<0>(acc[4*q+3] + b4.w);
        }
        __syncthreads();
    }

    // ---------------- layers 1..9: h @ Ws[L-1] + bs[L-1] ----------------
    auto layerF = [&](const float* __restrict__ W, const float* __restrict__ b,
                      auto mtag) {
        constexpr int M = decltype(mtag)::value;
        float acc[64];
        #pragma unroll
        for (int q = 0; q < 64; ++q) acc[q] = 0.0f;
        #pragma unroll 2
        for (int k = 0; k < HID; ++k) {
            const float a = h[k][p];
            const float4* wr = (const float4*)(W + k * HID + j0);
            #pragma unroll
            for (int q = 0; q < 16; ++q) {
                float4 w = wr[q];
                acc[4*q+0] = fmaf(a, w.x, acc[4*q+0]);
                acc[4*q+1] = fmaf(a, w.y, acc[4*q+1]);
                acc[4*q+2] = fmaf(a, w.z, acc[4*q+2]);
                acc[4*q+3] = fmaf(a, w.w, acc[4*q+3]);
            }
        }
        __syncthreads();   // all reads of h done before overwrite
        #pragma unroll
        for (int q = 0; q < 16; ++q) {
            float4 b4 = *(const float4*)(b + j0 + 4*q);
            h[j0+4*q+0][p] = act<M>(acc[4*q+0] + b4.x);
            h[j0+4*q+1][p] = act<M>(acc[4*q+1] + b4.y);
            h[j0+4*q+2][p] = act<M>(acc[4*q+2] + b4.z);
            h[j0+4*q+3][p] = act<M>(acc[4*q+3] + b4.w);
        }
        __syncthreads();
    };

    layerF(Ws + 0*65536, bs + 0*256, std::integral_constant<int,1>{});
    layerF(Ws + 1*65536, bs + 1*256, std::integral_constant<int,2>{});
    layerF(Ws + 2*65536, bs + 2*256, std::integral_constant<int,3>{});
    layerF(Ws + 3*65536, bs + 3*256, std::integral_constant<int,0>{});
    layerF(Ws + 4*65536, bs + 4*256, std::integral_constant<int,1>{});
    layerF(Ws + 5*65536, bs + 5*256, std::integral_constant<int,2>{});
    layerF(Ws + 6*65536, bs + 6*256, std::integral_constant<int,3>{});
    layerF(Ws + 7*65536, bs + 7*256, std::integral_constant<int,0>{});
    layerF(Ws + 8*65536, bs + 8*256, std::integral_constant<int,1>{});

    // ---------------- output: h @ Wout + bout, sigmoid ----------------
    if (tid < 192) {
        const int pp = tid & 63;
        const int c  = tid >> 6;            // 0..2
        const long pgo = (long)blockIdx.x * PTS + pp;
        if (pgo < n) {
            float z = bout[c];
            #pragma unroll 4
            for (int k = 0; k < HID; ++k)
                z = fmaf(h[k][pp], Wout[k * 3 + c], z);
            out[pgo * 3 + c] = 1.0f / (1.0f + __expf(-z));
        }
    }
}

extern "C" void kernel_launch(void* const* d_in, const int* in_sizes, int n_in,
                              void* d_out, int out_size, void* d_ws, size_t ws_size,
                              hipStream_t stream) {
    const float* x    = (const float*)d_in[0];
    const float* W0   = (const float*)d_in[1];
    const float* b0   = (const float*)d_in[2];
    const float* Ws   = (const float*)d_in[3];
    const float* bs   = (const float*)d_in[4];
    const float* Wout = (const float*)d_in[5];
    const float* bout = (const float*)d_in[6];
    float* out = (float*)d_out;

    const int n = in_sizes[0] / 12;          // number of points
    const int grid = (n + PTS - 1) / PTS;    // 2048 for N=131072

    cppn_fused<<<grid, 256, 0, stream>>>(x, W0, b0, Ws, bs, Wout, bout, out, n);
}

// Round 2
// 1898.990 us; speedup vs baseline: 1.3280x; 1.3280x over previous
//
#include <hip/hip_runtime.h>
#include <type_traits>

#define HID 256
#define PTS 64          // points per block
#define NTHREADS 512    // 8 waves; each wave owns a 32-wide output slice

// activation selector: m = layer % 4 : 0 sin, 1 cos, 2 gaussian, 3 tanh
template <int M>
__device__ __forceinline__ float act(float z) {
    if constexpr (M == 0) return __sinf(z);
    else if constexpr (M == 1) return __cosf(z);
    else if constexpr (M == 2) return __expf(-z * z);
    else { float e = __expf(2.0f * z); return 1.0f - 2.0f / (e + 1.0f); }
}

__global__ __launch_bounds__(NTHREADS, 4) void cppn_fused(
    const float* __restrict__ x,    // (N,12)
    const float* __restrict__ W0,   // (12,256)
    const float* __restrict__ b0,   // (256,)
    const float* __restrict__ Ws,   // (9,256,256)
    const float* __restrict__ bs,   // (9,256)
    const float* __restrict__ Wout, // (256,3)
    const float* __restrict__ bout, // (3,)
    float* __restrict__ out,        // (N,3)
    int n)
{
    __shared__ float h[HID][PTS];   // 64 KB; h[k][p]: lane-consecutive, conflict-free

    const int tid  = threadIdx.x;
    const int p    = tid & 63;                                        // lane = point
    const int j0   = __builtin_amdgcn_readfirstlane((tid >> 6) << 5); // wave's 32-out slice
    const long pg  = (long)blockIdx.x * PTS + p;                      // global point
    const bool live = (pg < n);

    // ---------------- layer 0: x(12) @ W0 + b0, sin ----------------
    {
        float xv[12];
        if (live) {
            const float4* xr = (const float4*)(x + pg * 12);
            float4 a = xr[0], b = xr[1], c = xr[2];
            xv[0]=a.x; xv[1]=a.y; xv[2]=a.z;  xv[3]=a.w;
            xv[4]=b.x; xv[5]=b.y; xv[6]=b.z;  xv[7]=b.w;
            xv[8]=c.x; xv[9]=c.y; xv[10]=c.z; xv[11]=c.w;
        } else {
            #pragma unroll
            for (int k = 0; k < 12; ++k) xv[k] = 0.0f;
        }
        float acc[32];
        #pragma unroll
        for (int q = 0; q < 32; ++q) acc[q] = 0.0f;
        #pragma unroll
        for (int k = 0; k < 12; ++k) {
            const float a = xv[k];
            const float4* wr = (const float4*)(W0 + k * HID + j0);
            #pragma unroll
            for (int q = 0; q < 8; ++q) {
                float4 w = wr[q];
                acc[4*q+0] = fmaf(a, w.x, acc[4*q+0]);
                acc[4*q+1] = fmaf(a, w.y, acc[4*q+1]);
                acc[4*q+2] = fmaf(a, w.z, acc[4*q+2]);
                acc[4*q+3] = fmaf(a, w.w, acc[4*q+3]);
            }
        }
        #pragma unroll
        for (int q = 0; q < 8; ++q) {
            float4 b4 = *(const float4*)(b0 + j0 + 4*q);
            h[j0+4*q+0][p] = act<0>(acc[4*q+0] + b4.x);
            h[j0+4*q+1][p] = act<0>(acc[4*q+1] + b4.y);
            h[j0+4*q+2][p] = act<0>(acc[4*q+2] + b4.z);
            h[j0+4*q+3][p] = act<0>(acc[4*q+3] + b4.w);
        }
        __syncthreads();
    }

    // ---------------- layers 1..9: h @ Ws[L-1] + bs[L-1] ----------------
    auto layerF = [&](const float* __restrict__ W, const float* __restrict__ b,
                      auto mtag) {
        constexpr int M = decltype(mtag)::value;
        float acc[32];
        #pragma unroll
        for (int q = 0; q < 32; ++q) acc[q] = 0.0f;
        #pragma unroll 2
        for (int k = 0; k < HID; ++k) {
            const float a = h[k][p];
            const float4* wr = (const float4*)(W + k * HID + j0);
            #pragma unroll
            for (int q = 0; q < 8; ++q) {
                float4 w = wr[q];
                acc[4*q+0] = fmaf(a, w.x, acc[4*q+0]);
                acc[4*q+1] = fmaf(a, w.y, acc[4*q+1]);
                acc[4*q+2] = fmaf(a, w.z, acc[4*q+2]);
                acc[4*q+3] = fmaf(a, w.w, acc[4*q+3]);
            }
        }
        __syncthreads();   // all reads of h done before overwrite
        #pragma unroll
        for (int q = 0; q < 8; ++q) {
            float4 b4 = *(const float4*)(b + j0 + 4*q);
            h[j0+4*q+0][p] = act<M>(acc[4*q+0] + b4.x);
            h[j0+4*q+1][p] = act<M>(acc[4*q+1] + b4.y);
            h[j0+4*q+2][p] = act<M>(acc[4*q+2] + b4.z);
            h[j0+4*q+3][p] = act<M>(acc[4*q+3] + b4.w);
        }
        __syncthreads();
    };

    layerF(Ws + 0*65536, bs + 0*256, std::integral_constant<int,1>{});
    layerF(Ws + 1*65536, bs + 1*256, std::integral_constant<int,2>{});
    layerF(Ws + 2*65536, bs + 2*256, std::integral_constant<int,3>{});
    layerF(Ws + 3*65536, bs + 3*256, std::integral_constant<int,0>{});
    layerF(Ws + 4*65536, bs + 4*256, std::integral_constant<int,1>{});
    layerF(Ws + 5*65536, bs + 5*256, std::integral_constant<int,2>{});
    layerF(Ws + 6*65536, bs + 6*256, std::integral_constant<int,3>{});
    layerF(Ws + 7*65536, bs + 7*256, std::integral_constant<int,0>{});
    layerF(Ws + 8*65536, bs + 8*256, std::integral_constant<int,1>{});

    // ---------------- output: h @ Wout + bout, sigmoid ----------------
    if (tid < 192) {
        const int pp = tid & 63;
        const int c  = tid >> 6;            // 0..2
        const long pgo = (long)blockIdx.x * PTS + pp;
        if (pgo < n) {
            float z = bout[c];
            #pragma unroll 4
            for (int k = 0; k < HID; ++k)
                z = fmaf(h[k][pp], Wout[k * 3 + c], z);
            out[pgo * 3 + c] = 1.0f / (1.0f + __expf(-z));
        }
    }
}

extern "C" void kernel_launch(void* const* d_in, const int* in_sizes, int n_in,
                              void* d_out, int out_size, void* d_ws, size_t ws_size,
                              hipStream_t stream) {
    const float* x    = (const float*)d_in[0];
    const float* W0   = (const float*)d_in[1];
    const float* b0   = (const float*)d_in[2];
    const float* Ws   = (const float*)d_in[3];
    const float* bs   = (const float*)d_in[4];
    const float* Wout = (const float*)d_in[5];
    const float* bout = (const float*)d_in[6];
    float* out = (float*)d_out;

    const int n = in_sizes[0] / 12;          // number of points
    const int grid = (n + PTS - 1) / PTS;    // 2048 for N=131072

    cppn_fused<<<grid, NTHREADS, 0, stream>>>(x, W0, b0, Ws, bs, Wout, bout, out, n);
}